// Round 11
// baseline (102.043 us; speedup 1.0000x reference)
//
#include <hip/hip_runtime.h>

// Chamfer loss: pred [8,4096,3] f32, gt [8,4096,3] f32 -> scalar f32.
//
// Budget (R9/R11/R14 reconciliation): fill ~41us + ~23 tiny harness
// restore-dispatches (~15-20us of launch gaps; fill ords are ~26 apart ->
// ~25 dispatches/iter) are fixed. Addressable: A (matrix-pipe floor
// 3.4us = 262144 MFMA x 32cyc/SIMD / 1024 SIMD, + ~2.5us VALU) and B
// (~3-4us). R14 (uniform B addressing + 2-deep prefetch) = 78.4us,
// absmax 0.0078.
// R16 = R15 resubmit (R15 died on a compile error: cvt_pkrtz returns an
// __fp16 ext-vector, not _Float16 ext-vector; fixed the receiving type).
//  1. s_setprio(1/0) around the MFMA pair (T5: main loop is barrier-free,
//     8 waves/SIMD at diverse phases -> arbitration pays there).
//  2. staging pack via v_cvt_pkrtz_f16_f32 (1 inst vs ~4; saves ~70
//     VALU/thread). RTZ doubles staged-g rounding: absmax -> ~0.016,
//     still 2x under the 0.033 threshold.
// Everything else byte-identical to R14 (passed).

#define BATCH 8
#define NPTS  4096
#define NPTS2 2048             // g-points per A-block (half the set)
#define TOPK  2048
#define BT    256
#define BTB   1024
#define NROW  (2 * BATCH)      // 16 rows = b*2+dir

typedef _Float16 half8 __attribute__((ext_vector_type(8)));
typedef __fp16 fp16x2 __attribute__((ext_vector_type(2)));
typedef float floatx16 __attribute__((ext_vector_type(16)));

static __device__ inline unsigned pack_h2(float a, float b) {
  fp16x2 r = __builtin_amdgcn_cvt_pkrtz(a, b);   // v_cvt_pkrtz_f16_f32
  return __builtin_bit_cast(unsigned, r);
}

static __device__ inline float amin3(float a, float b, float c) {
  float d;
  asm("v_min3_f32 %0, %1, %2, %3" : "=v"(d) : "v"(a), "v"(b), "v"(c));
  return d;
}

// ---------------- Kernel A: min squared distance via 32x32x16 MFMA ---------
// grid (64, 2, 16) = 2048 blocks -> 8 blocks/CU. Block: 64 q x 2048 g.
// Wave: 32 q x 1024 g (16 paired iterations).
__global__ __launch_bounds__(BT, 8) void nn_min_kernel(
    const float* __restrict__ pred, const float* __restrict__ gt,
    float* __restrict__ minsq, float* __restrict__ out) {
  const int row  = blockIdx.z;         // b*2 + dir
  const int half = blockIdx.y;         // which 2048 g-points
  const int b    = row >> 1;
  const int dir  = row & 1;
  const float* q = (dir == 0 ? pred : gt) + (size_t)b * NPTS * 3;
  const float* g = (dir == 0 ? gt : pred) + (size_t)b * NPTS * 3 +
                   (size_t)half * NPTS2 * 3;

  // gsh: staged f16x4 g-points (16384 B), dead after main loop.
  // scr: per-pair transpose scratch [pair][q 0..31][col 0..63 pad->68]
  // (17408 B) -> union size 17408 B. Separated by a barrier.
  union __align__(16) SharedU {
    uint2 gsh[NPTS2];
    float scr[2][32][68];
  };
  __shared__ SharedU sh;
  const int tid = threadIdx.x;

  // Stage 2048 g-points: 4 pts/thread/chunk via 3x float4 loads -> 2x b128.
#pragma unroll
  for (int c = 0; c < 2; c++) {
    int p = c * 1024 + tid * 4;                      // 4 consecutive points
    const float4* src = (const float4*)(g + 3 * p);  // 12 floats, 16B-aligned
    float4 f0 = src[0], f1 = src[1], f2 = src[2];
    float x0 = f0.x, y0 = f0.y, z0 = f0.z;
    float x1 = f0.w, y1 = f1.x, z1 = f1.y;
    float x2 = f1.z, y2 = f1.w, z2 = f2.x;
    float x3 = f2.y, y3 = f2.z, z3 = f2.w;
    uint2 u0 = make_uint2(pack_h2(-2.f * x0, -2.f * y0),
                          pack_h2(-2.f * z0, x0 * x0 + y0 * y0 + z0 * z0));
    uint2 u1 = make_uint2(pack_h2(-2.f * x1, -2.f * y1),
                          pack_h2(-2.f * z1, x1 * x1 + y1 * y1 + z1 * z1));
    uint2 u2 = make_uint2(pack_h2(-2.f * x2, -2.f * y2),
                          pack_h2(-2.f * z2, x2 * x2 + y2 * y2 + z2 * z2));
    uint2 u3 = make_uint2(pack_h2(-2.f * x3, -2.f * y3),
                          pack_h2(-2.f * z3, x3 * x3 + y3 * y3 + z3 * z3));
    *(uint4*)&sh.gsh[p]     = make_uint4(u0.x, u0.y, u1.x, u1.y);
    *(uint4*)&sh.gsh[p + 2] = make_uint4(u2.x, u2.y, u3.x, u3.y);
  }
  if (tid == 0 && blockIdx.x == 0 && blockIdx.y == 0 && blockIdx.z == 0)
    out[0] = 0.0f;                     // select accumulates into out

  const int lane = tid & 63;
  const int wave = tid >> 6;
  const int col  = lane & 31;          // n (g) index within tile
  const int hi   = lane >> 5;          // k-half / row-half selector
  const int pair = wave >> 1;                      // q-group pair id
  const int qg   = blockIdx.x * 2 + pair;          // q-group of 32
  const int gh   = wave & 1;                       // g-sub-half (1024 pts)
  const int q0   = qg * 32;

  // A fragment: lane l<32 holds A[m=l][k=0..7] = (qx,qy,qz,1,0,0,0,0);
  // lanes>=32 (k=8..15 rows) are zero -> their B operand x 0 = exact +0.
  half8 afrag = {};
  float qnv = 0.0f;
  if (lane < 32) {
    int qi = q0 + lane;
    float qx = q[3 * qi + 0], qy = q[3 * qi + 1], qz = q[3 * qi + 2];
    qnv = qx * qx + qy * qy + qz * qz;
    afrag[0] = (_Float16)qx;
    afrag[1] = (_Float16)qy;
    afrag[2] = (_Float16)qz;
    afrag[3] = (_Float16)1.0f;
  }
  __syncthreads();

  // Uniform addressing for ALL 64 lanes (lanes>=32 broadcast-read the same
  // addresses as lanes<32; their products are A-zeroed in the MFMA).
  const char* lds = (const char*)sh.gsh;
  int off = gh * 8192 + col * 8;

  float macc[16];
  floatx16 zc;
#pragma unroll
  for (int i = 0; i < 16; i++) { macc[i] = 3.0e38f; zc[i] = 0.0f; }

  // 32 g-tiles of 32, paired; ds_read prefetch 2 iterations (~128cy) ahead.
  // Deepest prefetch address: gh=1,col=31,t=15 -> 17400+8 = 17408 B =
  // exactly the union size (in-bounds); those values are never consumed.
  uint2 w0 = *(const uint2*)(lds + off);
  uint2 w1 = *(const uint2*)(lds + off + 256);
  uint2 w2 = *(const uint2*)(lds + off + 512);
  uint2 w3 = *(const uint2*)(lds + off + 768);
  off += 1024;
#pragma unroll 4
  for (int t = 0; t < 16; t++) {
    uint2 n0 = *(const uint2*)(lds + off);        // loads for t+2, issued
    uint2 n1 = *(const uint2*)(lds + off + 256);  // before the MFMA block
    off += 512;
    union { int4 i; half8 h; } b0, b1;
    b0.i = make_int4((int)w0.x, (int)w0.y, 0, 0);
    b1.i = make_int4((int)w1.x, (int)w1.y, 0, 0);
    __builtin_amdgcn_s_setprio(1);
    floatx16 r0 = __builtin_amdgcn_mfma_f32_32x32x16_f16(afrag, b0.h, zc, 0, 0, 0);
    floatx16 r1 = __builtin_amdgcn_mfma_f32_32x32x16_f16(afrag, b1.h, zc, 0, 0, 0);
    __builtin_amdgcn_s_setprio(0);
#pragma unroll
    for (int i = 0; i < 16; i++)
      macc[i] = amin3(macc[i], r0[i], r1[i]);
    w0 = w2; w1 = w3; w2 = n0; w3 = n1;
  }

  // -------- epilogue: LDS transpose + register tree (no butterfly) --------
  __syncthreads();                     // all main loops done; gsh dead

  // C/D layout: col=lane&31 (g), q-row=(i&3)+8*(i>>2)+4*hi. Write the
  // pair's 32x64 min-matrix: scr[pair][qrow][col + 32*gh]. Banks: rows q
  // and q+4 disjoint -> 2 touches/bank = free.
#pragma unroll
  for (int i = 0; i < 16; i++) {
    int qrow = (i & 3) + 8 * (i >> 2) + 4 * hi;
    sh.scr[pair][qrow][col + 32 * gh] = macc[i];
  }
  __syncthreads();

  // Even wave of each pair reduces its 32 rows over 64 cols and stores.
  if (gh == 0) {
    const int r = lane & 31;           // q-row handled by this lane
    const int h = lane >> 5;           // which 32-col half
    const float4* rp = (const float4*)&sh.scr[pair][r][h * 32];
    float4 m4 = rp[0];
#pragma unroll
    for (int k = 1; k < 8; k++) {
      float4 a = rp[k];
      m4.x = fminf(m4.x, a.x); m4.y = fminf(m4.y, a.y);
      m4.z = fminf(m4.z, a.z); m4.w = fminf(m4.w, a.w);
    }
    float m = fminf(amin3(m4.x, m4.y, m4.z), m4.w);
    m = fminf(m, __shfl_xor(m, 32));   // combine the two col-halves
    if (h == 0) {
      // lane r owns q-row r: qnv is this lane's own exact fp32 |q|^2
      minsq[((size_t)row * 2 + half) * NPTS + q0 + r] = fmaxf(qnv + m, 0.0f);
    }
  }
}

// ---------------- Kernel B: min-combine halves, sqrt, mean, top-k ----------
// block = 1024 (PER=4); 15-round radix on bits 30..16 (truncated-pivot-exact
// tie formula). 16 blocks, one per row.
__global__ __launch_bounds__(BTB) void select_kernel(
    const float* __restrict__ minsq, float* __restrict__ out) {
  const int row = blockIdx.x;                // 0..15 = b*2+dir
  const float* h0 = minsq + (size_t)row * 2 * NPTS;
  const float* h1 = h0 + NPTS;
  const int tid = threadIdx.x;

  __shared__ float sf[16];
  __shared__ int   si[16];
  __shared__ float s_fbc;
  __shared__ int   s_ibc;

  const int PER = NPTS / BTB;  // 4 values per thread
  float d[PER];
  float sum_all = 0.0f;
#pragma unroll
  for (int j = 0; j < PER; j++) {
    int idx = tid + BTB * j;
    float v = sqrtf(fminf(h0[idx], h1[idx]));
    d[j] = v;
    sum_all += v;
  }

  // block float sum of sum_all
  {
    float v = sum_all;
    for (int off = 32; off > 0; off >>= 1) v += __shfl_down(v, off);
    if ((tid & 63) == 0) sf[tid >> 6] = v;
    __syncthreads();
    if (tid == 0) {
      float s = 0.0f;
#pragma unroll
      for (int k = 0; k < 16; k++) s += sf[k];
      s_fbc = s;
    }
    __syncthreads();
    sum_all = s_fbc;
  }

  // radix-select the TOPK-th largest over top-15 float bits (nonneg values)
  unsigned sel = 0u;
  for (int bit = 30; bit >= 16; --bit) {
    unsigned cand = sel | (1u << bit);
    int c = 0;
#pragma unroll
    for (int j = 0; j < PER; j++) c += (__float_as_uint(d[j]) >= cand) ? 1 : 0;
    for (int off = 32; off > 0; off >>= 1) c += __shfl_down(c, off);
    if ((tid & 63) == 0) si[tid >> 6] = c;
    __syncthreads();
    if (tid == 0) {
      int s = 0;
#pragma unroll
      for (int k = 0; k < 16; k++) s += si[k];
      s_ibc = s;
    }
    __syncthreads();
    if (s_ibc >= TOPK) sel = cand;
  }

  // sum of strictly-greater values + count (full-precision compare)
  int cgt = 0;
  float sgt = 0.0f;
#pragma unroll
  for (int j = 0; j < PER; j++) {
    if (__float_as_uint(d[j]) > sel) { cgt++; sgt += d[j]; }
  }
  {
    float v = sgt;
    for (int off = 32; off > 0; off >>= 1) v += __shfl_down(v, off);
    if ((tid & 63) == 0) sf[tid >> 6] = v;
    int c = cgt;
    for (int off = 32; off > 0; off >>= 1) c += __shfl_down(c, off);
    if ((tid & 63) == 0) si[tid >> 6] = c;
    __syncthreads();
    if (tid == 0) {
      float s = 0.0f;
      int cs = 0;
#pragma unroll
      for (int k = 0; k < 16; k++) { s += sf[k]; cs += si[k]; }
      float kth = __uint_as_float(sel);
      // exact under truncated pivot: corrects the tie overcount
      float topk_sum = s + (float)(TOPK - cs) * kth;
      float rowval = sum_all / (float)NPTS + 3.0f * (topk_sum / (float)TOPK);
      atomicAdd(out, rowval * (1.0f / (float)BATCH));
    }
  }
}

extern "C" void kernel_launch(void* const* d_in, const int* in_sizes, int n_in,
                              void* d_out, int out_size, void* d_ws, size_t ws_size,
                              hipStream_t stream) {
  const float* pred = (const float*)d_in[0];
  const float* gt   = (const float*)d_in[1];
  float* out = (float*)d_out;
  float* minsq = (float*)d_ws;   // [NROW][2][NPTS] = 512 KB

  dim3 gridA(NPTS / 64, 2, NROW);   // 2048 blocks -> 8/CU
  nn_min_kernel<<<gridA, BT, 0, stream>>>(pred, gt, minsq, out);
  select_kernel<<<NROW, BTB, 0, stream>>>(minsq, out);
}

// Round 12
// 78.323 us; speedup vs baseline: 1.3028x; 1.3028x over previous
//
#include <hip/hip_runtime.h>

// Chamfer loss: pred [8,4096,3] f32, gt [8,4096,3] f32 -> scalar f32.
//
// Session ledger: R14 (uniform B-addr + 2-deep ds prefetch) = 78.4us best,
// absmax 0.0078. R16 (= R14 + setprio + pkrtz) = 102us on a slow container
// (fills 47 vs 41) -> ~12us genuine regression. Suspect: s_setprio toggles
// around each MFMA pair act as compiler scheduling fences, pinning the
// prefetch ds_reads and un-pipelining the loop (consistent with the
// documented GEMM-null/negative setprio result). pkrtz only removes VALU.
// R17 = R14 + pkrtz ONLY (single-variable isolation; setprio dropped).
// Predicted: ~75-80us, absmax 0.0156 (RTZ stage rounding, 2x under thr).

#define BATCH 8
#define NPTS  4096
#define NPTS2 2048             // g-points per A-block (half the set)
#define TOPK  2048
#define BT    256
#define BTB   1024
#define NROW  (2 * BATCH)      // 16 rows = b*2+dir

typedef _Float16 half8 __attribute__((ext_vector_type(8)));
typedef __fp16 fp16x2 __attribute__((ext_vector_type(2)));
typedef float floatx16 __attribute__((ext_vector_type(16)));

static __device__ inline unsigned pack_h2(float a, float b) {
  fp16x2 r = __builtin_amdgcn_cvt_pkrtz(a, b);   // v_cvt_pkrtz_f16_f32
  return __builtin_bit_cast(unsigned, r);
}

static __device__ inline float amin3(float a, float b, float c) {
  float d;
  asm("v_min3_f32 %0, %1, %2, %3" : "=v"(d) : "v"(a), "v"(b), "v"(c));
  return d;
}

// ---------------- Kernel A: min squared distance via 32x32x16 MFMA ---------
// grid (64, 2, 16) = 2048 blocks -> 8 blocks/CU. Block: 64 q x 2048 g.
// Wave: 32 q x 1024 g (16 paired iterations).
__global__ __launch_bounds__(BT, 8) void nn_min_kernel(
    const float* __restrict__ pred, const float* __restrict__ gt,
    float* __restrict__ minsq, float* __restrict__ out) {
  const int row  = blockIdx.z;         // b*2 + dir
  const int half = blockIdx.y;         // which 2048 g-points
  const int b    = row >> 1;
  const int dir  = row & 1;
  const float* q = (dir == 0 ? pred : gt) + (size_t)b * NPTS * 3;
  const float* g = (dir == 0 ? gt : pred) + (size_t)b * NPTS * 3 +
                   (size_t)half * NPTS2 * 3;

  // gsh: staged f16x4 g-points (16384 B), dead after main loop.
  // scr: per-pair transpose scratch [pair][q 0..31][col 0..63 pad->68]
  // (17408 B) -> union size 17408 B. Separated by a barrier.
  union __align__(16) SharedU {
    uint2 gsh[NPTS2];
    float scr[2][32][68];
  };
  __shared__ SharedU sh;
  const int tid = threadIdx.x;

  // Stage 2048 g-points: 4 pts/thread/chunk via 3x float4 loads -> 2x b128.
#pragma unroll
  for (int c = 0; c < 2; c++) {
    int p = c * 1024 + tid * 4;                      // 4 consecutive points
    const float4* src = (const float4*)(g + 3 * p);  // 12 floats, 16B-aligned
    float4 f0 = src[0], f1 = src[1], f2 = src[2];
    float x0 = f0.x, y0 = f0.y, z0 = f0.z;
    float x1 = f0.w, y1 = f1.x, z1 = f1.y;
    float x2 = f1.z, y2 = f1.w, z2 = f2.x;
    float x3 = f2.y, y3 = f2.z, z3 = f2.w;
    uint2 u0 = make_uint2(pack_h2(-2.f * x0, -2.f * y0),
                          pack_h2(-2.f * z0, x0 * x0 + y0 * y0 + z0 * z0));
    uint2 u1 = make_uint2(pack_h2(-2.f * x1, -2.f * y1),
                          pack_h2(-2.f * z1, x1 * x1 + y1 * y1 + z1 * z1));
    uint2 u2 = make_uint2(pack_h2(-2.f * x2, -2.f * y2),
                          pack_h2(-2.f * z2, x2 * x2 + y2 * y2 + z2 * z2));
    uint2 u3 = make_uint2(pack_h2(-2.f * x3, -2.f * y3),
                          pack_h2(-2.f * z3, x3 * x3 + y3 * y3 + z3 * z3));
    *(uint4*)&sh.gsh[p]     = make_uint4(u0.x, u0.y, u1.x, u1.y);
    *(uint4*)&sh.gsh[p + 2] = make_uint4(u2.x, u2.y, u3.x, u3.y);
  }
  if (tid == 0 && blockIdx.x == 0 && blockIdx.y == 0 && blockIdx.z == 0)
    out[0] = 0.0f;                     // select accumulates into out

  const int lane = tid & 63;
  const int wave = tid >> 6;
  const int col  = lane & 31;          // n (g) index within tile
  const int hi   = lane >> 5;          // k-half / row-half selector
  const int pair = wave >> 1;                      // q-group pair id
  const int qg   = blockIdx.x * 2 + pair;          // q-group of 32
  const int gh   = wave & 1;                       // g-sub-half (1024 pts)
  const int q0   = qg * 32;

  // A fragment: lane l<32 holds A[m=l][k=0..7] = (qx,qy,qz,1,0,0,0,0);
  // lanes>=32 (k=8..15 rows) are zero -> their B operand x 0 = exact +0.
  half8 afrag = {};
  float qnv = 0.0f;
  if (lane < 32) {
    int qi = q0 + lane;
    float qx = q[3 * qi + 0], qy = q[3 * qi + 1], qz = q[3 * qi + 2];
    qnv = qx * qx + qy * qy + qz * qz;
    afrag[0] = (_Float16)qx;
    afrag[1] = (_Float16)qy;
    afrag[2] = (_Float16)qz;
    afrag[3] = (_Float16)1.0f;
  }
  __syncthreads();

  // Uniform addressing for ALL 64 lanes (lanes>=32 broadcast-read the same
  // addresses as lanes<32; their products are A-zeroed in the MFMA).
  const char* lds = (const char*)sh.gsh;
  int off = gh * 8192 + col * 8;

  float macc[16];
  floatx16 zc;
#pragma unroll
  for (int i = 0; i < 16; i++) { macc[i] = 3.0e38f; zc[i] = 0.0f; }

  // 32 g-tiles of 32, paired; ds_read prefetch 2 iterations (~128cy) ahead.
  // Deepest prefetch address: gh=1,col=31,t=15 -> 17400+8 = 17408 B =
  // exactly the union size (in-bounds); those values are never consumed.
  uint2 w0 = *(const uint2*)(lds + off);
  uint2 w1 = *(const uint2*)(lds + off + 256);
  uint2 w2 = *(const uint2*)(lds + off + 512);
  uint2 w3 = *(const uint2*)(lds + off + 768);
  off += 1024;
#pragma unroll 4
  for (int t = 0; t < 16; t++) {
    uint2 n0 = *(const uint2*)(lds + off);        // loads for t+2, issued
    uint2 n1 = *(const uint2*)(lds + off + 256);  // before the MFMA block
    off += 512;
    union { int4 i; half8 h; } b0, b1;
    b0.i = make_int4((int)w0.x, (int)w0.y, 0, 0);
    b1.i = make_int4((int)w1.x, (int)w1.y, 0, 0);
    floatx16 r0 = __builtin_amdgcn_mfma_f32_32x32x16_f16(afrag, b0.h, zc, 0, 0, 0);
    floatx16 r1 = __builtin_amdgcn_mfma_f32_32x32x16_f16(afrag, b1.h, zc, 0, 0, 0);
#pragma unroll
    for (int i = 0; i < 16; i++)
      macc[i] = amin3(macc[i], r0[i], r1[i]);
    w0 = w2; w1 = w3; w2 = n0; w3 = n1;
  }

  // -------- epilogue: LDS transpose + register tree (no butterfly) --------
  __syncthreads();                     // all main loops done; gsh dead

  // C/D layout: col=lane&31 (g), q-row=(i&3)+8*(i>>2)+4*hi. Write the
  // pair's 32x64 min-matrix: scr[pair][qrow][col + 32*gh]. Banks: rows q
  // and q+4 disjoint -> 2 touches/bank = free.
#pragma unroll
  for (int i = 0; i < 16; i++) {
    int qrow = (i & 3) + 8 * (i >> 2) + 4 * hi;
    sh.scr[pair][qrow][col + 32 * gh] = macc[i];
  }
  __syncthreads();

  // Even wave of each pair reduces its 32 rows over 64 cols and stores.
  if (gh == 0) {
    const int r = lane & 31;           // q-row handled by this lane
    const int h = lane >> 5;           // which 32-col half
    const float4* rp = (const float4*)&sh.scr[pair][r][h * 32];
    float4 m4 = rp[0];
#pragma unroll
    for (int k = 1; k < 8; k++) {
      float4 a = rp[k];
      m4.x = fminf(m4.x, a.x); m4.y = fminf(m4.y, a.y);
      m4.z = fminf(m4.z, a.z); m4.w = fminf(m4.w, a.w);
    }
    float m = fminf(amin3(m4.x, m4.y, m4.z), m4.w);
    m = fminf(m, __shfl_xor(m, 32));   // combine the two col-halves
    if (h == 0) {
      // lane r owns q-row r: qnv is this lane's own exact fp32 |q|^2
      minsq[((size_t)row * 2 + half) * NPTS + q0 + r] = fmaxf(qnv + m, 0.0f);
    }
  }
}

// ---------------- Kernel B: min-combine halves, sqrt, mean, top-k ----------
// block = 1024 (PER=4); 15-round radix on bits 30..16 (truncated-pivot-exact
// tie formula). 16 blocks, one per row.
__global__ __launch_bounds__(BTB) void select_kernel(
    const float* __restrict__ minsq, float* __restrict__ out) {
  const int row = blockIdx.x;                // 0..15 = b*2+dir
  const float* h0 = minsq + (size_t)row * 2 * NPTS;
  const float* h1 = h0 + NPTS;
  const int tid = threadIdx.x;

  __shared__ float sf[16];
  __shared__ int   si[16];
  __shared__ float s_fbc;
  __shared__ int   s_ibc;

  const int PER = NPTS / BTB;  // 4 values per thread
  float d[PER];
  float sum_all = 0.0f;
#pragma unroll
  for (int j = 0; j < PER; j++) {
    int idx = tid + BTB * j;
    float v = sqrtf(fminf(h0[idx], h1[idx]));
    d[j] = v;
    sum_all += v;
  }

  // block float sum of sum_all
  {
    float v = sum_all;
    for (int off = 32; off > 0; off >>= 1) v += __shfl_down(v, off);
    if ((tid & 63) == 0) sf[tid >> 6] = v;
    __syncthreads();
    if (tid == 0) {
      float s = 0.0f;
#pragma unroll
      for (int k = 0; k < 16; k++) s += sf[k];
      s_fbc = s;
    }
    __syncthreads();
    sum_all = s_fbc;
  }

  // radix-select the TOPK-th largest over top-15 float bits (nonneg values)
  unsigned sel = 0u;
  for (int bit = 30; bit >= 16; --bit) {
    unsigned cand = sel | (1u << bit);
    int c = 0;
#pragma unroll
    for (int j = 0; j < PER; j++) c += (__float_as_uint(d[j]) >= cand) ? 1 : 0;
    for (int off = 32; off > 0; off >>= 1) c += __shfl_down(c, off);
    if ((tid & 63) == 0) si[tid >> 6] = c;
    __syncthreads();
    if (tid == 0) {
      int s = 0;
#pragma unroll
      for (int k = 0; k < 16; k++) s += si[k];
      s_ibc = s;
    }
    __syncthreads();
    if (s_ibc >= TOPK) sel = cand;
  }

  // sum of strictly-greater values + count (full-precision compare)
  int cgt = 0;
  float sgt = 0.0f;
#pragma unroll
  for (int j = 0; j < PER; j++) {
    if (__float_as_uint(d[j]) > sel) { cgt++; sgt += d[j]; }
  }
  {
    float v = sgt;
    for (int off = 32; off > 0; off >>= 1) v += __shfl_down(v, off);
    if ((tid & 63) == 0) sf[tid >> 6] = v;
    int c = cgt;
    for (int off = 32; off > 0; off >>= 1) c += __shfl_down(c, off);
    if ((tid & 63) == 0) si[tid >> 6] = c;
    __syncthreads();
    if (tid == 0) {
      float s = 0.0f;
      int cs = 0;
#pragma unroll
      for (int k = 0; k < 16; k++) { s += sf[k]; cs += si[k]; }
      float kth = __uint_as_float(sel);
      // exact under truncated pivot: corrects the tie overcount
      float topk_sum = s + (float)(TOPK - cs) * kth;
      float rowval = sum_all / (float)NPTS + 3.0f * (topk_sum / (float)TOPK);
      atomicAdd(out, rowval * (1.0f / (float)BATCH));
    }
  }
}

extern "C" void kernel_launch(void* const* d_in, const int* in_sizes, int n_in,
                              void* d_out, int out_size, void* d_ws, size_t ws_size,
                              hipStream_t stream) {
  const float* pred = (const float*)d_in[0];
  const float* gt   = (const float*)d_in[1];
  float* out = (float*)d_out;
  float* minsq = (float*)d_ws;   // [NROW][2][NPTS] = 512 KB

  dim3 gridA(NPTS / 64, 2, NROW);   // 2048 blocks -> 8/CU
  nn_min_kernel<<<gridA, BT, 0, stream>>>(pred, gt, minsq, out);
  select_kernel<<<NROW, BTB, 0, stream>>>(minsq, out);
}